// Round 9
// baseline (66.103 us; speedup 1.0000x reference)
//
#include <hip/hip_runtime.h>

#define IMG 512
#define HW (IMG * IMG)      // 262144
#define NB 257              // bins
#define BATCH 16
#define GX 16               // blocks per image
#define RPB 32              // rows per block (512/16)
#define THREADS 512         // 8 waves, 4 rows per wave
#define NBLOCKS (GX * BATCH)  // 256 total (power of 2 -> modular arrival trick)

// plane(h,w): h==0||w==0 -> 256; else 255 - min(m_h, d_w),
// m_h = min(h-1,511-h), d_w = min(w-1,511-w).
// Row h>=1: w=0 -> bin 256; d_w < m_h -> ramp bin 255-d_w (distinct addrs
// within the wave); d_w >= m_h -> constant bin 255-m_h (wave-reduced).

__global__ __launch_bounds__(THREADS) void fused_kernel(const float* __restrict__ x,
                                                        const float* __restrict__ mask_n,
                                                        float* __restrict__ out,
                                                        float* __restrict__ partial,
                                                        unsigned int* __restrict__ counter) {
    const int gx   = blockIdx.x;        // 0..15  (row-group)
    const int b    = blockIdx.y;        // 0..15  (image)
    const int wid  = threadIdx.x >> 6;  // 0..7
    const int lane = threadIdx.x & 63;

    __shared__ float bins[NB];
    for (int i = threadIdx.x; i < NB; i += THREADS) bins[i] = 0.f;
    __syncthreads();

    const float* xbase = x + (size_t)b * 3 * HW;
    const int h0 = gx * RPB + (wid << 2);   // 4 consecutive rows per wave
    const int wA = (lane << 2);             // pixels [wA, wA+3] (left half)
    const int wB = wA + 256;                // pixels [wB, wB+3] (right half)

#pragma unroll
    for (int rr = 0; rr < 4; ++rr) {
        const int h = h0 + rr;
        const float* xr  = xbase + (size_t)h * IMG;
        const float* xg  = xr + HW;
        const float* xbl = xg + HW;

        const float4 rA = *reinterpret_cast<const float4*>(xr  + wA);
        const float4 gA = *reinterpret_cast<const float4*>(xg  + wA);
        const float4 bA = *reinterpret_cast<const float4*>(xbl + wA);
        const float4 rB = *reinterpret_cast<const float4*>(xr  + wB);
        const float4 gB = *reinterpret_cast<const float4*>(xg  + wB);
        const float4 bB = *reinterpret_cast<const float4*>(xbl + wB);

        float mgA[4], mgB[4];
        mgA[0] = 20.f * (0.299f * rA.x + 0.587f * gA.x + 0.114f * bA.x);
        mgA[1] = 20.f * (0.299f * rA.y + 0.587f * gA.y + 0.114f * bA.y);
        mgA[2] = 20.f * (0.299f * rA.z + 0.587f * gA.z + 0.114f * bA.z);
        mgA[3] = 20.f * (0.299f * rA.w + 0.587f * gA.w + 0.114f * bA.w);
        mgB[0] = 20.f * (0.299f * rB.x + 0.587f * gB.x + 0.114f * bB.x);
        mgB[1] = 20.f * (0.299f * rB.y + 0.587f * gB.y + 0.114f * bB.y);
        mgB[2] = 20.f * (0.299f * rB.z + 0.587f * gB.z + 0.114f * bB.z);
        mgB[3] = 20.f * (0.299f * rB.w + 0.587f * gB.w + 0.114f * bB.w);

        const int m = min(h - 1, 511 - h);   // meaningful for h>=1
        float mid = 0.f;

        if (h == 0) {
            mid = mgA[0] + mgA[1] + mgA[2] + mgA[3] +
                  mgB[0] + mgB[1] + mgB[2] + mgB[3];
        } else {
#pragma unroll
            for (int t = 0; t < 4; ++t) {
                const int w = wA + t;
                if (w == 0) {
                    atomicAdd(&bins[256], mgA[t]);            // lane 0 only
                } else {
                    const int d = min(w - 1, 511 - w);
                    if (d >= m) mid += mgA[t];
                    else        atomicAdd(&bins[255 - d], mgA[t]);
                }
            }
#pragma unroll
            for (int t = 0; t < 4; ++t) {
                const int w = wB + t;
                const int d = min(w - 1, 511 - w);            // w>=256, never 0
                if (d >= m) mid += mgB[t];
                else        atomicAdd(&bins[255 - d], mgB[t]);
            }
        }

        // per-row wave butterfly: middle-run sum -> one LDS atomic per row
#pragma unroll
        for (int off = 32; off > 0; off >>= 1) mid += __shfl_down(mid, off, 64);
        if (lane == 0) atomicAdd(&bins[(h == 0) ? 256 : (255 - m)], mid);
    }
    __syncthreads();

    // plain coalesced partial store — every slot written, poison-safe
    float* pp = partial + ((size_t)b * GX + gx) * NB;
    for (int i = threadIdx.x; i < NB; i += THREADS) pp[i] = bins[i];

    // R8 bug: thread 0 could increment the counter while other threads of this
    // block were still storing partials. Barrier first (drains vmcnt -> all of
    // this block's stores have completed), THEN release-fence + arrival add.
    __syncthreads();
    __threadfence();   // release: make this block's partial stores visible

    // ---- arrival: the 256th arriving block of THIS call runs finalize ----
    // (old+1) % 256 == 0 fires exactly once per 256 increments regardless of
    // the counter's initial value -> immune to 0xAA ws poison, no reset node.
    __shared__ unsigned int is_last;
    if (threadIdx.x == 0) {
        const unsigned int old = atomicAdd(counter, 1u);
        is_last = (((old + 1u) & (NBLOCKS - 1u)) == 0u) ? 1u : 0u;
    }
    __syncthreads();
    if (!is_last) return;

    __threadfence();   // acquire: make all blocks' partial stores visible

    __shared__ float red_min[8];
    __shared__ float red_max[8];

    // BATCH*NB = 4112 = 8*512 + 16 -> 9 guarded strips of 512
    float lmin = 3.402823466e+38f, lmax = -3.402823466e+38f;
    float v[9];
#pragma unroll
    for (int k = 0; k < 9; ++k) {
        const int i = threadIdx.x + (k << 9);
        if (i < BATCH * NB) {
            const int bb = i / NB;
            const int l  = i - bb * NB;
            const float* p = partial + (size_t)bb * GX * NB + l;
            float s = 0.f;
#pragma unroll
            for (int g = 0; g < GX; ++g) s += p[(size_t)g * NB];
            s /= mask_n[l];
            v[k] = s;
            lmin = fminf(lmin, s);
            lmax = fmaxf(lmax, s);
        } else {
            v[k] = 0.f;
        }
    }
#pragma unroll
    for (int off = 32; off > 0; off >>= 1) {
        lmin = fminf(lmin, __shfl_xor(lmin, off, 64));
        lmax = fmaxf(lmax, __shfl_xor(lmax, off, 64));
    }
    if (lane == 0) { red_min[wid] = lmin; red_max[wid] = lmax; }
    __syncthreads();

    float pmin = red_min[0], pmax = red_max[0];
#pragma unroll
    for (int k = 1; k < 8; ++k) {
        pmin = fminf(pmin, red_min[k]);
        pmax = fmaxf(pmax, red_max[k]);
    }
    const float inv = 1.f / (pmax - pmin);
#pragma unroll
    for (int k = 0; k < 9; ++k) {
        const int i = threadIdx.x + (k << 9);
        if (i < BATCH * NB) out[i] = (v[k] - pmin) * inv;
    }
}

extern "C" void kernel_launch(void* const* d_in, const int* in_sizes, int n_in,
                              void* d_out, int out_size, void* d_ws, size_t ws_size,
                              hipStream_t stream) {
    const float* x      = (const float*)d_in[0];   // [16,3,512,512] f32
    const float* mask_n = (const float*)d_in[2];   // [257] f32 (mask d_in[1] unused)
    float* out     = (float*)d_out;                // [16,257] f32
    float* partial = (float*)d_ws;                 // [256,257] f32 (263 KB)
    unsigned int* counter = (unsigned int*)(partial + (size_t)NBLOCKS * NB);

    fused_kernel<<<dim3(GX, BATCH), THREADS, 0, stream>>>(x, mask_n, out, partial, counter);
}

// Round 10
// 36.920 us; speedup vs baseline: 1.7905x; 1.7905x over previous
//
#include <hip/hip_runtime.h>

#define IMG 512
#define HW (IMG * IMG)      // 262144
#define NB 257              // bins
#define BATCH 16
#define GX 32               // blocks per image
#define RPB 16              // rows per block (512/32)
#define THREADS 512         // 8 waves, 2 rows per wave

// plane(h,w): h==0||w==0 -> 256; else 255 - min(m_h, d_w),
// m_h = min(h-1,511-h), d_w = min(w-1,511-w).
// Row h>=1: w=0 -> bin 256; d_w < m_h -> ramp bin 255-d_w (distinct addrs
// within the wave); d_w >= m_h -> constant bin 255-m_h (wave-reduced).

__global__ __launch_bounds__(THREADS) void hist_kernel(const float* __restrict__ x,
                                                       float* __restrict__ partial) {
    const int gx   = blockIdx.x;        // 0..31  (row-group)
    const int b    = blockIdx.y;        // 0..15  (image)
    const int wid  = threadIdx.x >> 6;  // 0..7
    const int lane = threadIdx.x & 63;

    __shared__ float bins[NB];
    for (int i = threadIdx.x; i < NB; i += THREADS) bins[i] = 0.f;
    __syncthreads();

    const float* xbase = x + (size_t)b * 3 * HW;
    const int h0 = gx * RPB + (wid << 1);   // 2 consecutive rows per wave
    const int wA = (lane << 2);             // pixels [wA, wA+3] (left half)
    const int wB = wA + 256;                // pixels [wB, wB+3] (right half)

#pragma unroll
    for (int rr = 0; rr < 2; ++rr) {
        const int h = h0 + rr;
        const float* xr  = xbase + (size_t)h * IMG;
        const float* xg  = xr + HW;
        const float* xbl = xg + HW;

        const float4 rA = *reinterpret_cast<const float4*>(xr  + wA);
        const float4 gA = *reinterpret_cast<const float4*>(xg  + wA);
        const float4 bA = *reinterpret_cast<const float4*>(xbl + wA);
        const float4 rB = *reinterpret_cast<const float4*>(xr  + wB);
        const float4 gB = *reinterpret_cast<const float4*>(xg  + wB);
        const float4 bB = *reinterpret_cast<const float4*>(xbl + wB);

        float mgA[4], mgB[4];
        mgA[0] = 20.f * (0.299f * rA.x + 0.587f * gA.x + 0.114f * bA.x);
        mgA[1] = 20.f * (0.299f * rA.y + 0.587f * gA.y + 0.114f * bA.y);
        mgA[2] = 20.f * (0.299f * rA.z + 0.587f * gA.z + 0.114f * bA.z);
        mgA[3] = 20.f * (0.299f * rA.w + 0.587f * gA.w + 0.114f * bA.w);
        mgB[0] = 20.f * (0.299f * rB.x + 0.587f * gB.x + 0.114f * bB.x);
        mgB[1] = 20.f * (0.299f * rB.y + 0.587f * gB.y + 0.114f * bB.y);
        mgB[2] = 20.f * (0.299f * rB.z + 0.587f * gB.z + 0.114f * bB.z);
        mgB[3] = 20.f * (0.299f * rB.w + 0.587f * gB.w + 0.114f * bB.w);

        const int m = min(h - 1, 511 - h);   // meaningful for h>=1
        float mid = 0.f;

        if (h == 0) {
            mid = mgA[0] + mgA[1] + mgA[2] + mgA[3] +
                  mgB[0] + mgB[1] + mgB[2] + mgB[3];
        } else {
#pragma unroll
            for (int t = 0; t < 4; ++t) {
                const int w = wA + t;
                if (w == 0) {
                    atomicAdd(&bins[256], mgA[t]);            // lane 0 only
                } else {
                    const int d = min(w - 1, 511 - w);
                    if (d >= m) mid += mgA[t];
                    else        atomicAdd(&bins[255 - d], mgA[t]);
                }
            }
#pragma unroll
            for (int t = 0; t < 4; ++t) {
                const int w = wB + t;
                const int d = min(w - 1, 511 - w);            // w>=256, never 0
                if (d >= m) mid += mgB[t];
                else        atomicAdd(&bins[255 - d], mgB[t]);
            }
        }

        // per-row wave butterfly: middle-run sum -> one LDS atomic per row
#pragma unroll
        for (int off = 32; off > 0; off >>= 1) mid += __shfl_down(mid, off, 64);
        if (lane == 0) atomicAdd(&bins[(h == 0) ? 256 : (255 - m)], mid);
    }
    __syncthreads();

    // plain coalesced partial store — every slot written, poison-safe
    float* pp = partial + ((size_t)b * GX + gx) * NB;
    for (int i = threadIdx.x; i < NB; i += THREADS) pp[i] = bins[i];
}

__global__ __launch_bounds__(1024) void finalize_kernel(const float* __restrict__ partial,
                                                        const float* __restrict__ mask_n,
                                                        float* __restrict__ out) {
    __shared__ float red_min[16];
    __shared__ float red_max[16];
    const int lane = threadIdx.x & 63;
    const int wv   = threadIdx.x >> 6;

    // BATCH*NB = 4112 = 4*1024 + 16 -> 5 guarded strips
    float lmin = 3.402823466e+38f, lmax = -3.402823466e+38f;
    float v[5];
#pragma unroll
    for (int k = 0; k < 5; ++k) {
        const int i = threadIdx.x + (k << 10);
        if (i < BATCH * NB) {
            const int bb = i / NB;
            const int l  = i - bb * NB;
            const float* p = partial + (size_t)bb * GX * NB + l;
            float s = 0.f;
#pragma unroll 8
            for (int g = 0; g < GX; ++g) s += p[(size_t)g * NB];
            s /= mask_n[l];
            v[k] = s;
            lmin = fminf(lmin, s);
            lmax = fmaxf(lmax, s);
        } else {
            v[k] = 0.f;
        }
    }
#pragma unroll
    for (int off = 32; off > 0; off >>= 1) {
        lmin = fminf(lmin, __shfl_xor(lmin, off, 64));
        lmax = fmaxf(lmax, __shfl_xor(lmax, off, 64));
    }
    if (lane == 0) { red_min[wv] = lmin; red_max[wv] = lmax; }
    __syncthreads();

    float pmin = red_min[0], pmax = red_max[0];
#pragma unroll
    for (int k = 1; k < 16; ++k) {
        pmin = fminf(pmin, red_min[k]);
        pmax = fmaxf(pmax, red_max[k]);
    }
    const float inv = 1.f / (pmax - pmin);
#pragma unroll
    for (int k = 0; k < 5; ++k) {
        const int i = threadIdx.x + (k << 10);
        if (i < BATCH * NB) out[i] = (v[k] - pmin) * inv;
    }
}

extern "C" void kernel_launch(void* const* d_in, const int* in_sizes, int n_in,
                              void* d_out, int out_size, void* d_ws, size_t ws_size,
                              hipStream_t stream) {
    const float* x      = (const float*)d_in[0];   // [16,3,512,512] f32
    const float* mask_n = (const float*)d_in[2];   // [257] f32 (mask d_in[1] unused)
    float* out     = (float*)d_out;                // [16,257] f32
    float* partial = (float*)d_ws;                 // [16*32,257] f32 (526 KB)

    hist_kernel<<<dim3(GX, BATCH), THREADS, 0, stream>>>(x, partial);
    finalize_kernel<<<1, 1024, 0, stream>>>(partial, mask_n, out);
}

// Round 11
// 35.239 us; speedup vs baseline: 1.8759x; 1.0477x over previous
//
#include <hip/hip_runtime.h>

#define IMG 512
#define HW (IMG * IMG)      // 262144
#define NB 257              // bins
#define BATCH 16
#define GX 16               // blocks per image
#define RPB 32              // rows per block (512/16)
#define THREADS 512         // 8 waves, 4 rows per wave

// plane(h,w): h==0||w==0 -> 256; else 255 - min(m_h, d_w),
// m_h = min(h-1,511-h), d_w = min(w-1,511-w).
// Row h>=1: w=0 -> bin 256; d_w < m_h -> ramp bin 255-d_w (distinct addrs
// within the wave); d_w >= m_h -> constant bin 255-m_h (wave-reduced).
//
// Best measured config (R7: 35.39 us). Occupancy 2->32 waves/CU and atomic
// restructurings all land 35-42 us; kernel portion ~8 us = L3-BW-bound on
// the 50.3 MB stream; remainder is fixed graph-replay + node-boundary cost.

__global__ __launch_bounds__(THREADS) void hist_kernel(const float* __restrict__ x,
                                                       float* __restrict__ partial) {
    const int gx   = blockIdx.x;        // 0..15  (row-group)
    const int b    = blockIdx.y;        // 0..15  (image)
    const int wid  = threadIdx.x >> 6;  // 0..7
    const int lane = threadIdx.x & 63;

    __shared__ float bins[NB];
    for (int i = threadIdx.x; i < NB; i += THREADS) bins[i] = 0.f;
    __syncthreads();

    const float* xbase = x + (size_t)b * 3 * HW;
    const int h0 = gx * RPB + (wid << 2);   // 4 consecutive rows per wave
    const int wA = (lane << 2);             // pixels [wA, wA+3] (left half)
    const int wB = wA + 256;                // pixels [wB, wB+3] (right half)

#pragma unroll
    for (int rr = 0; rr < 4; ++rr) {
        const int h = h0 + rr;
        const float* xr  = xbase + (size_t)h * IMG;
        const float* xg  = xr + HW;
        const float* xbl = xg + HW;

        const float4 rA = *reinterpret_cast<const float4*>(xr  + wA);
        const float4 gA = *reinterpret_cast<const float4*>(xg  + wA);
        const float4 bA = *reinterpret_cast<const float4*>(xbl + wA);
        const float4 rB = *reinterpret_cast<const float4*>(xr  + wB);
        const float4 gB = *reinterpret_cast<const float4*>(xg  + wB);
        const float4 bB = *reinterpret_cast<const float4*>(xbl + wB);

        float mgA[4], mgB[4];
        mgA[0] = 20.f * (0.299f * rA.x + 0.587f * gA.x + 0.114f * bA.x);
        mgA[1] = 20.f * (0.299f * rA.y + 0.587f * gA.y + 0.114f * bA.y);
        mgA[2] = 20.f * (0.299f * rA.z + 0.587f * gA.z + 0.114f * bA.z);
        mgA[3] = 20.f * (0.299f * rA.w + 0.587f * gA.w + 0.114f * bA.w);
        mgB[0] = 20.f * (0.299f * rB.x + 0.587f * gB.x + 0.114f * bB.x);
        mgB[1] = 20.f * (0.299f * rB.y + 0.587f * gB.y + 0.114f * bB.y);
        mgB[2] = 20.f * (0.299f * rB.z + 0.587f * gB.z + 0.114f * bB.z);
        mgB[3] = 20.f * (0.299f * rB.w + 0.587f * gB.w + 0.114f * bB.w);

        const int m = min(h - 1, 511 - h);   // meaningful for h>=1
        float mid = 0.f;

        if (h == 0) {
            mid = mgA[0] + mgA[1] + mgA[2] + mgA[3] +
                  mgB[0] + mgB[1] + mgB[2] + mgB[3];
        } else {
#pragma unroll
            for (int t = 0; t < 4; ++t) {
                const int w = wA + t;
                if (w == 0) {
                    atomicAdd(&bins[256], mgA[t]);            // lane 0 only
                } else {
                    const int d = min(w - 1, 511 - w);
                    if (d >= m) mid += mgA[t];
                    else        atomicAdd(&bins[255 - d], mgA[t]);
                }
            }
#pragma unroll
            for (int t = 0; t < 4; ++t) {
                const int w = wB + t;
                const int d = min(w - 1, 511 - w);            // w>=256, never 0
                if (d >= m) mid += mgB[t];
                else        atomicAdd(&bins[255 - d], mgB[t]);
            }
        }

        // per-row wave butterfly: middle-run sum -> one LDS atomic per row
#pragma unroll
        for (int off = 32; off > 0; off >>= 1) mid += __shfl_down(mid, off, 64);
        if (lane == 0) atomicAdd(&bins[(h == 0) ? 256 : (255 - m)], mid);
    }
    __syncthreads();

    // plain coalesced partial store — every slot written, poison-safe
    float* pp = partial + ((size_t)b * GX + gx) * NB;
    for (int i = threadIdx.x; i < NB; i += THREADS) pp[i] = bins[i];
}

__global__ __launch_bounds__(1024) void finalize_kernel(const float* __restrict__ partial,
                                                        const float* __restrict__ mask_n,
                                                        float* __restrict__ out) {
    __shared__ float red_min[16];
    __shared__ float red_max[16];
    const int lane = threadIdx.x & 63;
    const int wv   = threadIdx.x >> 6;

    // BATCH*NB = 4112 = 4*1024 + 16 -> 5 guarded strips
    float lmin = 3.402823466e+38f, lmax = -3.402823466e+38f;
    float v[5];
#pragma unroll
    for (int k = 0; k < 5; ++k) {
        const int i = threadIdx.x + (k << 10);
        if (i < BATCH * NB) {
            const int bb = i / NB;
            const int l  = i - bb * NB;
            const float* p = partial + (size_t)bb * GX * NB + l;
            float s = 0.f;
#pragma unroll
            for (int g = 0; g < GX; ++g) s += p[(size_t)g * NB];
            s /= mask_n[l];
            v[k] = s;
            lmin = fminf(lmin, s);
            lmax = fmaxf(lmax, s);
        } else {
            v[k] = 0.f;
        }
    }
#pragma unroll
    for (int off = 32; off > 0; off >>= 1) {
        lmin = fminf(lmin, __shfl_xor(lmin, off, 64));
        lmax = fmaxf(lmax, __shfl_xor(lmax, off, 64));
    }
    if (lane == 0) { red_min[wv] = lmin; red_max[wv] = lmax; }
    __syncthreads();

    float pmin = red_min[0], pmax = red_max[0];
#pragma unroll
    for (int k = 1; k < 16; ++k) {
        pmin = fminf(pmin, red_min[k]);
        pmax = fmaxf(pmax, red_max[k]);
    }
    const float inv = 1.f / (pmax - pmin);
#pragma unroll
    for (int k = 0; k < 5; ++k) {
        const int i = threadIdx.x + (k << 10);
        if (i < BATCH * NB) out[i] = (v[k] - pmin) * inv;
    }
}

extern "C" void kernel_launch(void* const* d_in, const int* in_sizes, int n_in,
                              void* d_out, int out_size, void* d_ws, size_t ws_size,
                              hipStream_t stream) {
    const float* x      = (const float*)d_in[0];   // [16,3,512,512] f32
    const float* mask_n = (const float*)d_in[2];   // [257] f32 (mask d_in[1] unused)
    float* out     = (float*)d_out;                // [16,257] f32
    float* partial = (float*)d_ws;                 // [16*16,257] f32 (263 KB)

    hist_kernel<<<dim3(GX, BATCH), THREADS, 0, stream>>>(x, partial);
    finalize_kernel<<<1, 1024, 0, stream>>>(partial, mask_n, out);
}